// Round 13
// baseline (323.321 us; speedup 1.0000x reference)
//
#include <hip/hip_runtime.h>
#include <hip/hip_bf16.h>

// AdditiveAttention: B=8, Q=128, V=512, H=512.
// out = [context (B*Q*H) | weights (B*Q*V)] fp32.
// ws: Eq [1024*512] f32 @0, Ev [4096*512] f32 @2MB (10MB total).
// bc dropped (softmax shift-invariant); sum_h wc[h] const also cancels.
// Score math: tanh(y)=1-2r, r=1/(2^(C*y)+1), C=2*log2(e);
//   softmax arg = -C * sum_h wc[h]*r  (consts dropped).
// HARD RULE (R0..R5): NO min-occupancy arg in launch_bounds, ever.
// HARD RULE (R12): NO hand-written VOP3P packed-f32 inline asm (silent
//   wrong results). Packed f32 only via <2 x float> source, backend-lowered.
// HARD RULE (R14): NO host memory APIs in kernel_launch (R12's
//   hipMemsetAsync is the prime suspect for the container failure).
// R11: factorized exp (Ev/Eq stored by proj) -- WIN. R13: f32x2 packed -- WIN.
// R15: R14's fused score+finish retried WITHOUT the host memset: the 512
//   election counters (int at out_ctx[rowbase*512]) are zeroed by proj
//   block (0,0); stream order makes zeros visible before any atomicAdd.
//   kernel_launch is pure kernel launches again (the shape that passed 10x).

#define C_SCALE 2.8853900817779268f

typedef __attribute__((ext_vector_type(8))) short short8;
typedef __attribute__((ext_vector_type(4))) float f32x4;
typedef __attribute__((ext_vector_type(2))) float f32x2;

__device__ __forceinline__ float fexp2(float x) { return __builtin_amdgcn_exp2f(x); }
__device__ __forceinline__ float frcp(float x)  { return __builtin_amdgcn_rcpf(x); }

// fp32->bf16 split: hi = RNE(x); lo = trunc_bf16(x - hi).
__device__ __forceinline__ void bf_split(float x, short& hi, short& lo) {
  unsigned u = __builtin_bit_cast(unsigned, x);
  unsigned r = u + 0x7fffu + ((u >> 16) & 1u);
  hi = (short)(r >> 16);
  float hf = __builtin_bit_cast(float, r & 0xffff0000u);
  lo = (short)(__builtin_bit_cast(unsigned, x - hf) >> 16);
}

// ---------------- split-bf16 MFMA GEMM ---------------------------------------
// acc[m][n] = sum_k A[m][k]*W[n][k] + bias[n]; OUTPUT = exp2(C*acc)  (R11).
// 64x64 tile, KC=64. by<16 -> query rows (Eq), else values rows (Ev).
// LDS rows padded to 72 shorts (144B). Grid (8,80).
// Block (0,0) additionally zeroes the 512 election counters (R15).
__global__ __launch_bounds__(256) void proj_gemm_mfma(
    const float* __restrict__ query, const float* __restrict__ values,
    const float* __restrict__ Wq, const float* __restrict__ Wv,
    const float* __restrict__ bq, const float* __restrict__ bv,
    float* __restrict__ qp, float* __restrict__ vp,
    float* __restrict__ out_ctx)
{
  __shared__ short sAhi[64 * 72];
  __shared__ short sAlo[64 * 72];
  __shared__ short sWhi[64 * 72];
  __shared__ short sWlo[64 * 72];

  const int t    = threadIdx.x;
  const int lane = t & 63;
  const int w    = t >> 6;                  // wave 0..3
  const int by   = blockIdx.y;

  // R15: zero election counters (one int per qpair at out_ctx[rowbase*512]).
  // Kernel-boundary ordering publishes these before attn's atomicAdds.
  if (blockIdx.x == 0 && by == 0) {
#pragma unroll
    for (int i = 0; i < 2; ++i) {
      const int q = t + i * 256;            // qpair id 0..511
      const int bb = q >> 6, qg = q & 63;
      ((int*)out_ctx)[(size_t)(bb * 128 + qg * 2) * 512] = 0;
    }
  }

  const bool isQ = (by < 16);
  const float* A    = isQ ? query : values;
  const float* W    = isQ ? Wq : Wv;
  const float* bias = isQ ? bq : bv;
  float*       out  = isQ ? qp : vp;
  const int m0 = (isQ ? by : (by - 16)) << 6;
  const int n0 = blockIdx.x << 6;

  const int srow = t >> 2, scol = t & 3;
  const float* Ap = A + (size_t)(m0 + srow) * 512 + (scol << 2);
  const float* Wp = W + (size_t)(n0 + srow) * 512 + (scol << 2);

  const int mw = (w & 1) << 5, nw = (w >> 1) << 5;   // wave's 32x32 quadrant
  const int frow = lane & 15, fquad = lane >> 4;

  f32x4 acc[2][2] = {};
  float4 pfA[4], pfW[4];
#pragma unroll
  for (int p = 0; p < 4; ++p) {
    pfA[p] = *(const float4*)(Ap + (p << 4));
    pfW[p] = *(const float4*)(Wp + (p << 4));
  }

  for (int kc = 0; kc < 512; kc += 64) {
    __syncthreads();
#pragma unroll
    for (int p = 0; p < 4; ++p) {
      float av[4] = {pfA[p].x, pfA[p].y, pfA[p].z, pfA[p].w};
      float wv[4] = {pfW[p].x, pfW[p].y, pfW[p].z, pfW[p].w};
      short4 ah, al, wh, wl;
      short* ahp = (short*)&ah; short* alp = (short*)&al;
      short* whp = (short*)&wh; short* wlp = (short*)&wl;
#pragma unroll
      for (int k = 0; k < 4; ++k) {
        bf_split(av[k], ahp[k], alp[k]);
        bf_split(wv[k], whp[k], wlp[k]);
      }
      const int ofs = srow * 72 + ((p << 2) + scol) * 4;
      *(short4*)&sAhi[ofs] = ah; *(short4*)&sAlo[ofs] = al;
      *(short4*)&sWhi[ofs] = wh; *(short4*)&sWlo[ofs] = wl;
    }
    __syncthreads();
    if (kc + 64 < 512) {
#pragma unroll
      for (int p = 0; p < 4; ++p) {
        pfA[p] = *(const float4*)(Ap + kc + 64 + (p << 4));
        pfW[p] = *(const float4*)(Wp + kc + 64 + (p << 4));
      }
    }
#pragma unroll
    for (int kb = 0; kb < 2; ++kb) {
      const int ko = kb * 32 + fquad * 8;
      short8 ahi[2], alo[2], whi[2], wlo[2];
#pragma unroll
      for (int mt = 0; mt < 2; ++mt) {
        const int r = (mw + mt * 16 + frow) * 72 + ko;
        ahi[mt] = *(const short8*)&sAhi[r];
        alo[mt] = *(const short8*)&sAlo[r];
      }
#pragma unroll
      for (int nt = 0; nt < 2; ++nt) {
        const int r = (nw + nt * 16 + frow) * 72 + ko;
        whi[nt] = *(const short8*)&sWhi[r];
        wlo[nt] = *(const short8*)&sWlo[r];
      }
#pragma unroll
      for (int mt = 0; mt < 2; ++mt)
#pragma unroll
        for (int nt = 0; nt < 2; ++nt) {
          acc[mt][nt] = __builtin_amdgcn_mfma_f32_16x16x32_bf16(
              alo[mt], whi[nt], acc[mt][nt], 0, 0, 0);
          acc[mt][nt] = __builtin_amdgcn_mfma_f32_16x16x32_bf16(
              ahi[mt], wlo[nt], acc[mt][nt], 0, 0, 0);
          acc[mt][nt] = __builtin_amdgcn_mfma_f32_16x16x32_bf16(
              ahi[mt], whi[nt], acc[mt][nt], 0, 0, 0);
        }
    }
  }

  // epilogue: store exp2(C*(acc+bias)) (R11)
#pragma unroll
  for (int nt = 0; nt < 2; ++nt) {
    const int n = n0 + nw + nt * 16 + frow;
    const float bn = bias[n];
#pragma unroll
    for (int mt = 0; mt < 2; ++mt) {
      float vreg[4] = {acc[mt][nt].x, acc[mt][nt].y, acc[mt][nt].z, acc[mt][nt].w};
#pragma unroll
      for (int r = 0; r < 4; ++r) {
        const int m = m0 + mw + mt * 16 + fquad * 4 + r;
        out[(size_t)m * 512 + n] = fexp2(C_SCALE * (vreg[r] + bn));
      }
    }
  }
}

// ---------------- score chunk (NU slot-steps, 16 slots apart) ----------------
// f32x2 vector arithmetic (backend lowers to v_pk_*; NO inline asm).
template<int NU>
__device__ __forceinline__ void score_chunkC(
    const float* __restrict__ vpb,
    const f32x2 (&Eq0a)[8][2], const f32x2 (&Eq1a)[8][2], const f32x2 (&wca)[8][2],
    const int* idxs, float* __restrict__ ow0,
    int s00, int i0, int hi, int c4, int lane)
{
  int su[NU];
  unsigned voff[NU];
  f32x2 a0[NU], a1[NU];
#pragma unroll
  for (int u = 0; u < NU; ++u) {
    su[u] = s00 + ((i0 + u) << 4);
    voff[u] = ((unsigned)idxs[su[u] & 511] << 9) + (unsigned)c4;
    a0[u] = (f32x2){0.f, 0.f}; a1[u] = (f32x2){0.f, 0.f};
  }
  const f32x2 one2 = {1.f, 1.f};
#pragma unroll
  for (int j = 0; j < 8; ++j) {
    float4 vv[NU];
#pragma unroll
    for (int u = 0; u < NU; ++u)
      vv[u] = *(const float4*)(vpb + voff[u] + (unsigned)(j << 6));
#pragma unroll
    for (int u = 0; u < NU; ++u) {
      const f32x2 Ev[2] = {{vv[u].x, vv[u].y}, {vv[u].z, vv[u].w}};
#pragma unroll
      for (int kp = 0; kp < 2; ++kp) {
        f32x2 e0 = Ev[kp] * Eq0a[j][kp];
        f32x2 e1 = Ev[kp] * Eq1a[j][kp];
        f32x2 d0 = e0 + one2;
        f32x2 d1 = e1 + one2;
        f32x2 pr = d0 * d1;
        f32x2 P  = {frcp(pr.x), frcp(pr.y)};       // pair-rcp per q-pair
        a0[u] = __builtin_elementwise_fma(wca[j][kp] * d1, P, a0[u]);
        a1[u] = __builtin_elementwise_fma(wca[j][kp] * d0, P, a1[u]);
      }
    }
  }
#pragma unroll
  for (int u = 0; u < NU; ++u) {
    float s0 = a0[u].x + a0[u].y;
    float s1 = a1[u].x + a1[u].y;
#pragma unroll
    for (int off = 1; off < 16; off <<= 1) {
      s0 += __shfl_xor(s0, off, 64);
      s1 += __shfl_xor(s1, off, 64);
    }
    if (su[u] < hi && (lane & 15) == (i0 + u)) {   // i0+u <= 7 < 16
      ow0[su[u]]       = s0;
      ow0[512 + su[u]] = s1;
    }
  }
}

// ---------------- fused attn: raw scores + last-block finish -----------------
// Grid (512 qpairs, 4 slot-chunks) x 256 thr (4 waves). PLAIN launch_bounds.
// Score phase identical to R13. Election: each block fences its stores, t0
// atomicAdds the per-qpair counter at out_ctx[rowbase*512] (zeroed by proj;
// overwritten by the finisher's own context store). The block seeing old==3
// does softmax + weight rows + context. Correct under undefined dispatch
// order and cross-XCD non-coherence (device-scope atomics + __threadfence).
__global__ __launch_bounds__(256) void attn_score_finish(
    const float* __restrict__ qp, const float* __restrict__ vp,
    const float* __restrict__ values, const int* __restrict__ mask,
    const float* __restrict__ wc,
    float* __restrict__ out_ctx, float* __restrict__ out_w)
{
  __shared__ int   idxs[512];
  __shared__ int   cnt8[8];
  __shared__ float wls2[512][2];    // final weights per slot, (q0,q1) pairs
  __shared__ int   isLast;

  const int t    = threadIdx.x;
  const int lane = t & 63;
  const int w    = t >> 6;                 // 0..3
  const int b    = blockIdx.x & 7;
  const int qg   = blockIdx.x >> 3;
  const int rowbase = b * 128 + qg * 2;

  ((float*)wls2)[t]       = 0.f;
  ((float*)wls2)[t + 256] = 0.f;
  ((float*)wls2)[t + 512] = 0.f;
  ((float*)wls2)[t + 768] = 0.f;
  idxs[t] = 0; idxs[t + 256] = 0;
  const int mv0 = mask[b * 512 + t];
  const int mv1 = mask[b * 512 + 256 + t];
  const unsigned long long bal0 = __ballot(mv0 != 0);
  const unsigned long long bal1 = __ballot(mv1 != 0);
  if (lane == 0) { cnt8[w] = __popcll(bal0); cnt8[w + 4] = __popcll(bal1); }
  __syncthreads();
  int cnt = 0, off0 = 0, off4 = 0;
#pragma unroll
  for (int j = 0; j < 8; ++j) {
    if (j == w)     off0 = cnt;
    if (j == w + 4) off4 = cnt;
    cnt += cnt8[j];
  }
  int iinv0 = -1, iinv1 = -1;
  if (mv0) { iinv0 = off0 + __popcll(bal0 & ((1ull << lane) - 1ull)); idxs[iinv0] = t; }
  if (mv1) { iinv1 = off4 + __popcll(bal1 & ((1ull << lane) - 1ull)); idxs[iinv1] = t + 256; }
  __syncthreads();

  // ---- score phase (chunk c of 4)
  const int c  = blockIdx.y;
  const int lo = (cnt * c) >> 2;
  const int hi = (cnt * (c + 1)) >> 2;
  const int NI = (hi - lo + 15) >> 4;      // 16-slot steps (<=8)
  const int g  = lane >> 4;
  const int c4 = (lane & 15) << 2;
  const int s00 = lo + (w << 2) + g;

  const float* vpb = vp + (size_t)b * 512 * 512;
  const float* qr0 = qp + (size_t)rowbase * 512;
  float* ow0 = out_w + (size_t)rowbase * 512;

  f32x2 Eq0a[8][2], Eq1a[8][2], wca[8][2];
#pragma unroll
  for (int j = 0; j < 8; ++j) {
    const int hoff = (j << 6) + c4;
    const float4 q0v = *(const float4*)(qr0 + hoff);
    const float4 q1v = *(const float4*)(qr0 + 512 + hoff);
    const float4 wcv = *(const float4*)(wc + hoff);
    Eq0a[j][0] = (f32x2){q0v.x, q0v.y}; Eq0a[j][1] = (f32x2){q0v.z, q0v.w};
    Eq1a[j][0] = (f32x2){q1v.x, q1v.y}; Eq1a[j][1] = (f32x2){q1v.z, q1v.w};
    wca[j][0]  = (f32x2){wcv.x, wcv.y}; wca[j][1]  = (f32x2){wcv.z, wcv.w};
  }

  int i0 = 0;
  for (; i0 + 4 <= NI; i0 += 4)
    score_chunkC<4>(vpb, Eq0a, Eq1a, wca, idxs, ow0, s00, i0, hi, c4, lane);
  for (; i0 < NI; ++i0)
    score_chunkC<1>(vpb, Eq0a, Eq1a, wca, idxs, ow0, s00, i0, hi, c4, lane);

  // ---- election: last of the 4 chunk-blocks finishes the qpair
  __threadfence();                          // make this thread's stores visible
  __syncthreads();                          // all threads fenced
  if (t == 0) {
    int old = atomicAdd((int*)(out_ctx + (size_t)rowbase * 512), 1);
    isLast = (old == 3) ? 1 : 0;
  }
  __syncthreads();
  if (!isLast) return;
  __threadfence();                          // acquire: see other blocks' scores

  // ---- softmax: waves 0,1 -> q0; 2,3 -> q1 (dup x2; writers w==0, w==2)
  {
    const int mq = w >> 1;
    const float* srow = out_w + (size_t)(rowbase + mq) * 512;
    float4 u0 = ((const float4*)srow)[lane * 2];
    float4 u1 = ((const float4*)srow)[lane * 2 + 1];
    float s8[8] = {u0.x, u0.y, u0.z, u0.w, u1.x, u1.y, u1.z, u1.w};
#pragma unroll
    for (int k = 0; k < 8; ++k)
      if (lane * 8 + k >= cnt) s8[k] = 3.4e38f;           // mask garbage slots
    float m = s8[0];
#pragma unroll
    for (int k = 1; k < 8; ++k) m = fminf(m, s8[k]);      // min: weight=exp2(C*(m-s))
#pragma unroll
    for (int off = 1; off < 64; off <<= 1) m = fminf(m, __shfl_xor(m, off, 64));
    float e[8], S = 0.f;
#pragma unroll
    for (int k = 0; k < 8; ++k) { e[k] = fexp2(C_SCALE * (m - s8[k])); S += e[k]; }
#pragma unroll
    for (int off = 1; off < 64; off <<= 1) S += __shfl_xor(S, off, 64);
    const float rinv = frcp(S);
    if (w == 0 || w == 2) {
#pragma unroll
      for (int k = 0; k < 8; ++k) {
        const int s = lane * 8 + k;
        if (s < cnt) wls2[s][mq] = e[k] * rinv;
      }
    }
  }
  __syncthreads();

  // ---- final weight rows (coalesced; zeros where masked out)
  {
    float w00 = iinv0 >= 0 ? wls2[iinv0][0] : 0.f;
    float w01 = iinv0 >= 0 ? wls2[iinv0][1] : 0.f;
    float w10 = iinv1 >= 0 ? wls2[iinv1][0] : 0.f;
    float w11 = iinv1 >= 0 ? wls2[iinv1][1] : 0.f;
    out_w[(size_t)rowbase * 512 + t]             = w00;
    out_w[(size_t)(rowbase + 1) * 512 + t]       = w01;
    out_w[(size_t)rowbase * 512 + 256 + t]       = w10;
    out_w[(size_t)(rowbase + 1) * 512 + 256 + t] = w11;
  }

  // ---- context: wave w owns h-window [w*128, w*128+128)
  const int NC = (cnt + 3) >> 2;
  const unsigned hb0 = (unsigned)(w * 128 + c4);
  const float* vb = values + (size_t)b * 512 * 512;
  float c00[4] = {}, c01[4] = {}, c10[4] = {}, c11[4] = {};
#pragma unroll 4
  for (int i = 0; i < NC; ++i) {
    const int s = (i << 2) + g;
    const unsigned ro = ((unsigned)idxs[s] << 9);
    const float2 wg = *(const float2*)&wls2[s][0];        // padded slots: 0
    const float4 v0 = *(const float4*)(vb + ro + hb0);
    const float4 v1 = *(const float4*)(vb + ro + hb0 + 64);
    const float a0[4] = {v0.x, v0.y, v0.z, v0.w};
    const float a1[4] = {v1.x, v1.y, v1.z, v1.w};
#pragma unroll
    for (int k = 0; k < 4; ++k) {
      c00[k] = __builtin_fmaf(wg.x, a0[k], c00[k]);
      c01[k] = __builtin_fmaf(wg.x, a1[k], c01[k]);
      c10[k] = __builtin_fmaf(wg.y, a0[k], c10[k]);
      c11[k] = __builtin_fmaf(wg.y, a1[k], c11[k]);
    }
  }
#pragma unroll
  for (int k = 0; k < 4; ++k) {                           // reduce over g
    c00[k] += __shfl_xor(c00[k], 16, 64); c00[k] += __shfl_xor(c00[k], 32, 64);
    c01[k] += __shfl_xor(c01[k], 16, 64); c01[k] += __shfl_xor(c01[k], 32, 64);
    c10[k] += __shfl_xor(c10[k], 16, 64); c10[k] += __shfl_xor(c10[k], 32, 64);
    c11[k] += __shfl_xor(c11[k], 16, 64); c11[k] += __shfl_xor(c11[k], 32, 64);
  }
  if (lane < 16) {
    float4 o00 = {c00[0], c00[1], c00[2], c00[3]};
    float4 o01 = {c01[0], c01[1], c01[2], c01[3]};
    float4 o10 = {c10[0], c10[1], c10[2], c10[3]};
    float4 o11 = {c11[0], c11[1], c11[2], c11[3]};
    float* r0 = out_ctx + (size_t)rowbase * 512;
    float* r1 = out_ctx + (size_t)(rowbase + 1) * 512;
    *(float4*)(r0 + hb0)      = o00;   // lane 0, w==0 overwrites the counter
    *(float4*)(r0 + hb0 + 64) = o01;
    *(float4*)(r1 + hb0)      = o10;
    *(float4*)(r1 + hb0 + 64) = o11;
  }
}

extern "C" void kernel_launch(void* const* d_in, const int* in_sizes, int n_in,
                              void* d_out, int out_size, void* d_ws, size_t ws_size,
                              hipStream_t stream) {
  const float* query  = (const float*)d_in[0];
  const float* values = (const float*)d_in[1];
  const int*   mask   = (const int*)d_in[2];
  const float* Wq     = (const float*)d_in[3];
  const float* bq     = (const float*)d_in[4];
  const float* Wv     = (const float*)d_in[5];
  const float* bv     = (const float*)d_in[6];
  const float* wc     = (const float*)d_in[7];
  // d_in[8] = bc: no effect on outputs (softmax shift-invariance) -> dropped.

  float* out   = (float*)d_out;
  float* out_w = out + (size_t)8 * 128 * 512;
  float* qp    = (float*)d_ws;                 // Eq: 1024 x 512
  float* vp    = qp + (size_t)1024 * 512;      // Ev: 4096 x 512

  proj_gemm_mfma<<<dim3(8, 80), 256, 0, stream>>>(query, values, Wq, Wv, bq, bv,
                                                  qp, vp, out);
  attn_score_finish<<<dim3(512, 4), 256, 0, stream>>>(qp, vp, values, mask, wc,
                                                      out, out_w);
}

// Round 14
// 139.957 us; speedup vs baseline: 2.3101x; 2.3101x over previous
//
#include <hip/hip_runtime.h>
#include <hip/hip_bf16.h>

// AdditiveAttention: B=8, Q=128, V=512, H=512.
// out = [context (B*Q*H) | weights (B*Q*V)] fp32.
// ws: Eq [1024*512] f32 @0, Ev [4096*512] f32 @2MB; optional presplit
//   planes @10MB (Ahi/Alo 5120x512, Whi/Wlo 1024x512 bf16, +12.5MB).
// bc dropped (softmax shift-invariant); sum_h wc[h] const also cancels.
// Score math: tanh(y)=1-2r, r=1/(2^(C*y)+1), C=2*log2(e);
//   softmax arg = -C * sum_h wc[h]*r  (consts dropped).
// HARD RULE (R0..R5): NO min-occupancy arg in launch_bounds, ever.
// HARD RULE (R12): NO hand-written VOP3P packed-f32 inline asm.
// HARD RULE (R14): NO host memory APIs in kernel_launch (graph capture).
// HARD RULE (R15): NO per-block device-fence election (fused finish ran
//   242us vs 45us split -- __threadfence x2048 blocks serializes L2).
// R11 factorized exp, R13 f32x2 packed: WINs, retained.
// R16: presplit pass -- A re-split x8 and W re-split x16/64 across proj
//   blocks (~38M redundant bf_splits, ~40% of proj issue). presplit writes
//   bf16 hi/lo planes once; proj stages via short8 loads + ds_write_b128,
//   zero staging VALU. Runtime ws_size guard falls back to R13 proj.

#define C_SCALE 2.8853900817779268f

typedef __attribute__((ext_vector_type(8))) short short8;
typedef __attribute__((ext_vector_type(4))) float f32x4;
typedef __attribute__((ext_vector_type(2))) float f32x2;

__device__ __forceinline__ float fexp2(float x) { return __builtin_amdgcn_exp2f(x); }
__device__ __forceinline__ float frcp(float x)  { return __builtin_amdgcn_rcpf(x); }

// fp32->bf16 split: hi = RNE(x); lo = trunc_bf16(x - hi).
__device__ __forceinline__ void bf_split(float x, short& hi, short& lo) {
  unsigned u = __builtin_bit_cast(unsigned, x);
  unsigned r = u + 0x7fffu + ((u >> 16) & 1u);
  hi = (short)(r >> 16);
  float hf = __builtin_bit_cast(float, r & 0xffff0000u);
  lo = (short)(__builtin_bit_cast(unsigned, x - hf) >> 16);
}

// ---------------- presplit: f32 -> bf16 hi/lo planes (R16) -------------------
// A-plane rows: 0..1023 = query, 1024..5119 = values. W-plane rows:
// 0..511 = Wq, 512..1023 = Wv. 393216 octets exactly = 1536 x 256.
__global__ __launch_bounds__(256) void presplit(
    const float* __restrict__ query, const float* __restrict__ values,
    const float* __restrict__ Wq, const float* __restrict__ Wv,
    short* __restrict__ Ahi, short* __restrict__ Alo,
    short* __restrict__ Whi, short* __restrict__ Wlo)
{
  const size_t oct = (size_t)blockIdx.x * 256 + threadIdx.x;
  const float* src; short *dhi, *dlo;
  if (oct < 65536) {                        // query
    size_t o = oct * 8;
    src = query + o; dhi = Ahi + o; dlo = Alo + o;
  } else if (oct < 327680) {                // values
    size_t o = (oct - 65536) * 8;
    src = values + o;
    dhi = Ahi + (size_t)1024 * 512 + o; dlo = Alo + (size_t)1024 * 512 + o;
  } else if (oct < 360448) {                // Wq
    size_t o = (oct - 327680) * 8;
    src = Wq + o; dhi = Whi + o; dlo = Wlo + o;
  } else {                                  // Wv
    size_t o = (oct - 360448) * 8;
    src = Wv + o;
    dhi = Whi + (size_t)512 * 512 + o; dlo = Wlo + (size_t)512 * 512 + o;
  }
  float4 v0 = *(const float4*)src;
  float4 v1 = *(const float4*)(src + 4);
  const float f[8] = {v0.x, v0.y, v0.z, v0.w, v1.x, v1.y, v1.z, v1.w};
  short8 h, l;
  short* hp = (short*)&h; short* lp = (short*)&l;
#pragma unroll
  for (int k = 0; k < 8; ++k) bf_split(f[k], hp[k], lp[k]);
  *(short8*)dhi = h;
  *(short8*)dlo = l;
}

// ---------------- proj GEMM, presplit inputs (R16) ---------------------------
// acc[m][n] = sum_k A[m][k]*W[n][k] + bias[n]; OUTPUT = exp2(C*acc)  (R11).
// Staging = pure short8 load + ds_write_b128 (no VALU). Grid (8,80).
__global__ __launch_bounds__(256) void proj_gemm_pre(
    const short* __restrict__ Ahi, const short* __restrict__ Alo,
    const short* __restrict__ Whi, const short* __restrict__ Wlo,
    const float* __restrict__ bq, const float* __restrict__ bv,
    float* __restrict__ qp, float* __restrict__ vp)
{
  __shared__ short sAhi[64 * 72];
  __shared__ short sAlo[64 * 72];
  __shared__ short sWhi[64 * 72];
  __shared__ short sWlo[64 * 72];

  const int t    = threadIdx.x;
  const int lane = t & 63;
  const int w    = t >> 6;
  const int by   = blockIdx.y;
  const bool isQ = (by < 16);
  const float* bias = isQ ? bq : bv;
  float*       out  = isQ ? qp : vp;
  const int m0 = (isQ ? by : (by - 16)) << 6;
  const int n0 = blockIdx.x << 6;
  const int arow0 = isQ ? m0 : 1024 + m0;   // row in A-plane
  const int wrow0 = isQ ? n0 : 512 + n0;    // row in W-plane

  const int srow = t >> 2, c16 = (t & 3) << 4;
  const short* ApH = Ahi + (size_t)(arow0 + srow) * 512 + c16;
  const short* ApL = Alo + (size_t)(arow0 + srow) * 512 + c16;
  const short* WpH = Whi + (size_t)(wrow0 + srow) * 512 + c16;
  const short* WpL = Wlo + (size_t)(wrow0 + srow) * 512 + c16;

  const int mw = (w & 1) << 5, nw = (w >> 1) << 5;
  const int frow = lane & 15, fquad = lane >> 4;

  f32x4 acc[2][2] = {};
  short8 pAh[2], pAl[2], pWh[2], pWl[2];
#pragma unroll
  for (int p = 0; p < 2; ++p) {
    pAh[p] = *(const short8*)(ApH + p * 8);
    pAl[p] = *(const short8*)(ApL + p * 8);
    pWh[p] = *(const short8*)(WpH + p * 8);
    pWl[p] = *(const short8*)(WpL + p * 8);
  }

  for (int kc = 0; kc < 512; kc += 64) {
    __syncthreads();
    {
      const int ofs = srow * 72 + c16;
#pragma unroll
      for (int p = 0; p < 2; ++p) {
        *(short8*)&sAhi[ofs + p * 8] = pAh[p];
        *(short8*)&sAlo[ofs + p * 8] = pAl[p];
        *(short8*)&sWhi[ofs + p * 8] = pWh[p];
        *(short8*)&sWlo[ofs + p * 8] = pWl[p];
      }
    }
    __syncthreads();
    if (kc + 64 < 512) {
#pragma unroll
      for (int p = 0; p < 2; ++p) {
        pAh[p] = *(const short8*)(ApH + kc + 64 + p * 8);
        pAl[p] = *(const short8*)(ApL + kc + 64 + p * 8);
        pWh[p] = *(const short8*)(WpH + kc + 64 + p * 8);
        pWl[p] = *(const short8*)(WpL + kc + 64 + p * 8);
      }
    }
#pragma unroll
    for (int kb = 0; kb < 2; ++kb) {
      const int ko = kb * 32 + fquad * 8;
      short8 ahi[2], alo[2], whi[2], wlo[2];
#pragma unroll
      for (int mt = 0; mt < 2; ++mt) {
        const int r = (mw + mt * 16 + frow) * 72 + ko;
        ahi[mt] = *(const short8*)&sAhi[r];
        alo[mt] = *(const short8*)&sAlo[r];
      }
#pragma unroll
      for (int nt = 0; nt < 2; ++nt) {
        const int r = (nw + nt * 16 + frow) * 72 + ko;
        whi[nt] = *(const short8*)&sWhi[r];
        wlo[nt] = *(const short8*)&sWlo[r];
      }
#pragma unroll
      for (int mt = 0; mt < 2; ++mt)
#pragma unroll
        for (int nt = 0; nt < 2; ++nt) {
          acc[mt][nt] = __builtin_amdgcn_mfma_f32_16x16x32_bf16(
              alo[mt], whi[nt], acc[mt][nt], 0, 0, 0);
          acc[mt][nt] = __builtin_amdgcn_mfma_f32_16x16x32_bf16(
              ahi[mt], wlo[nt], acc[mt][nt], 0, 0, 0);
          acc[mt][nt] = __builtin_amdgcn_mfma_f32_16x16x32_bf16(
              ahi[mt], whi[nt], acc[mt][nt], 0, 0, 0);
        }
    }
  }

#pragma unroll
  for (int nt = 0; nt < 2; ++nt) {
    const int n = n0 + nw + nt * 16 + frow;
    const float bn = bias[n];
#pragma unroll
    for (int mt = 0; mt < 2; ++mt) {
      float vreg[4] = {acc[mt][nt].x, acc[mt][nt].y, acc[mt][nt].z, acc[mt][nt].w};
#pragma unroll
      for (int r = 0; r < 4; ++r) {
        const int m = m0 + mw + mt * 16 + fquad * 4 + r;
        out[(size_t)m * 512 + n] = fexp2(C_SCALE * (vreg[r] + bn));
      }
    }
  }
}

// ---------------- proj GEMM, raw-f32 fallback (R13) --------------------------
__global__ __launch_bounds__(256) void proj_gemm_mfma(
    const float* __restrict__ query, const float* __restrict__ values,
    const float* __restrict__ Wq, const float* __restrict__ Wv,
    const float* __restrict__ bq, const float* __restrict__ bv,
    float* __restrict__ qp, float* __restrict__ vp)
{
  __shared__ short sAhi[64 * 72];
  __shared__ short sAlo[64 * 72];
  __shared__ short sWhi[64 * 72];
  __shared__ short sWlo[64 * 72];

  const int t    = threadIdx.x;
  const int lane = t & 63;
  const int w    = t >> 6;
  const int by   = blockIdx.y;
  const bool isQ = (by < 16);
  const float* A    = isQ ? query : values;
  const float* W    = isQ ? Wq : Wv;
  const float* bias = isQ ? bq : bv;
  float*       out  = isQ ? qp : vp;
  const int m0 = (isQ ? by : (by - 16)) << 6;
  const int n0 = blockIdx.x << 6;

  const int srow = t >> 2, scol = t & 3;
  const float* Ap = A + (size_t)(m0 + srow) * 512 + (scol << 2);
  const float* Wp = W + (size_t)(n0 + srow) * 512 + (scol << 2);

  const int mw = (w & 1) << 5, nw = (w >> 1) << 5;
  const int frow = lane & 15, fquad = lane >> 4;

  f32x4 acc[2][2] = {};
  float4 pfA[4], pfW[4];
#pragma unroll
  for (int p = 0; p < 4; ++p) {
    pfA[p] = *(const float4*)(Ap + (p << 4));
    pfW[p] = *(const float4*)(Wp + (p << 4));
  }

  for (int kc = 0; kc < 512; kc += 64) {
    __syncthreads();
#pragma unroll
    for (int p = 0; p < 4; ++p) {
      float av[4] = {pfA[p].x, pfA[p].y, pfA[p].z, pfA[p].w};
      float wv[4] = {pfW[p].x, pfW[p].y, pfW[p].z, pfW[p].w};
      short4 ah, al, wh, wl;
      short* ahp = (short*)&ah; short* alp = (short*)&al;
      short* whp = (short*)&wh; short* wlp = (short*)&wl;
#pragma unroll
      for (int k = 0; k < 4; ++k) {
        bf_split(av[k], ahp[k], alp[k]);
        bf_split(wv[k], whp[k], wlp[k]);
      }
      const int ofs = srow * 72 + ((p << 2) + scol) * 4;
      *(short4*)&sAhi[ofs] = ah; *(short4*)&sAlo[ofs] = al;
      *(short4*)&sWhi[ofs] = wh; *(short4*)&sWlo[ofs] = wl;
    }
    __syncthreads();
    if (kc + 64 < 512) {
#pragma unroll
      for (int p = 0; p < 4; ++p) {
        pfA[p] = *(const float4*)(Ap + kc + 64 + (p << 4));
        pfW[p] = *(const float4*)(Wp + kc + 64 + (p << 4));
      }
    }
#pragma unroll
    for (int kb = 0; kb < 2; ++kb) {
      const int ko = kb * 32 + fquad * 8;
      short8 ahi[2], alo[2], whi[2], wlo[2];
#pragma unroll
      for (int mt = 0; mt < 2; ++mt) {
        const int r = (mw + mt * 16 + frow) * 72 + ko;
        ahi[mt] = *(const short8*)&sAhi[r];
        alo[mt] = *(const short8*)&sAlo[r];
      }
#pragma unroll
      for (int nt = 0; nt < 2; ++nt) {
        const int r = (nw + nt * 16 + frow) * 72 + ko;
        whi[nt] = *(const short8*)&sWhi[r];
        wlo[nt] = *(const short8*)&sWlo[r];
      }
#pragma unroll
      for (int mt = 0; mt < 2; ++mt)
#pragma unroll
        for (int nt = 0; nt < 2; ++nt) {
          acc[mt][nt] = __builtin_amdgcn_mfma_f32_16x16x32_bf16(
              alo[mt], whi[nt], acc[mt][nt], 0, 0, 0);
          acc[mt][nt] = __builtin_amdgcn_mfma_f32_16x16x32_bf16(
              ahi[mt], wlo[nt], acc[mt][nt], 0, 0, 0);
          acc[mt][nt] = __builtin_amdgcn_mfma_f32_16x16x32_bf16(
              ahi[mt], whi[nt], acc[mt][nt], 0, 0, 0);
        }
    }
  }

#pragma unroll
  for (int nt = 0; nt < 2; ++nt) {
    const int n = n0 + nw + nt * 16 + frow;
    const float bn = bias[n];
#pragma unroll
    for (int mt = 0; mt < 2; ++mt) {
      float vreg[4] = {acc[mt][nt].x, acc[mt][nt].y, acc[mt][nt].z, acc[mt][nt].w};
#pragma unroll
      for (int r = 0; r < 4; ++r) {
        const int m = m0 + mw + mt * 16 + fquad * 4 + r;
        out[(size_t)m * 512 + n] = fexp2(C_SCALE * (vreg[r] + bn));
      }
    }
  }
}

// ---------------- score chunk (NU slot-steps, 16 slots apart) ----------------
// f32x2 vector arithmetic (backend lowers to v_pk_*; NO inline asm).
template<int NU>
__device__ __forceinline__ void score_chunkC(
    const float* __restrict__ vpb,
    const f32x2 (&Eq0a)[8][2], const f32x2 (&Eq1a)[8][2], const f32x2 (&wca)[8][2],
    const int* idxs, float* __restrict__ ow0,
    int s00, int i0, int hi, int c4, int lane)
{
  int su[NU];
  unsigned voff[NU];
  f32x2 a0[NU], a1[NU];
#pragma unroll
  for (int u = 0; u < NU; ++u) {
    su[u] = s00 + ((i0 + u) << 4);
    voff[u] = ((unsigned)idxs[su[u] & 511] << 9) + (unsigned)c4;
    a0[u] = (f32x2){0.f, 0.f}; a1[u] = (f32x2){0.f, 0.f};
  }
  const f32x2 one2 = {1.f, 1.f};
#pragma unroll
  for (int j = 0; j < 8; ++j) {
    float4 vv[NU];
#pragma unroll
    for (int u = 0; u < NU; ++u)
      vv[u] = *(const float4*)(vpb + voff[u] + (unsigned)(j << 6));
#pragma unroll
    for (int u = 0; u < NU; ++u) {
      const f32x2 Ev[2] = {{vv[u].x, vv[u].y}, {vv[u].z, vv[u].w}};
#pragma unroll
      for (int kp = 0; kp < 2; ++kp) {
        f32x2 e0 = Ev[kp] * Eq0a[j][kp];
        f32x2 e1 = Ev[kp] * Eq1a[j][kp];
        f32x2 d0 = e0 + one2;
        f32x2 d1 = e1 + one2;
        f32x2 pr = d0 * d1;
        f32x2 P  = {frcp(pr.x), frcp(pr.y)};       // pair-rcp per q-pair
        a0[u] = __builtin_elementwise_fma(wca[j][kp] * d1, P, a0[u]);
        a1[u] = __builtin_elementwise_fma(wca[j][kp] * d0, P, a1[u]);
      }
    }
  }
#pragma unroll
  for (int u = 0; u < NU; ++u) {
    float s0 = a0[u].x + a0[u].y;
    float s1 = a1[u].x + a1[u].y;
#pragma unroll
    for (int off = 1; off < 16; off <<= 1) {
      s0 += __shfl_xor(s0, off, 64);
      s1 += __shfl_xor(s1, off, 64);
    }
    if (su[u] < hi && (lane & 15) == (i0 + u)) {   // i0+u <= 7 < 16
      ow0[su[u]]       = s0;
      ow0[512 + su[u]] = s1;
    }
  }
}

// ---------------- attn kernel A: raw scores ----------------------------------
// Grid (512 qpairs, 4 slot-chunks) x 256 thr (4 waves). PLAIN launch_bounds.
__global__ __launch_bounds__(256) void attn_score(
    const float* __restrict__ qp, const float* __restrict__ vp,
    const int* __restrict__ mask, const float* __restrict__ wc,
    float* __restrict__ out_w)
{
  __shared__ int idxs[512];
  __shared__ int cnt8[8];

  const int t    = threadIdx.x;
  const int lane = t & 63;
  const int w    = t >> 6;                 // 0..3
  const int b    = blockIdx.x & 7;
  const int qg   = blockIdx.x >> 3;
  const int rowbase = b * 128 + qg * 2;

  idxs[t] = 0; idxs[t + 256] = 0;
  const int mv0 = mask[b * 512 + t];
  const int mv1 = mask[b * 512 + 256 + t];
  const unsigned long long bal0 = __ballot(mv0 != 0);
  const unsigned long long bal1 = __ballot(mv1 != 0);
  if (lane == 0) { cnt8[w] = __popcll(bal0); cnt8[w + 4] = __popcll(bal1); }
  __syncthreads();
  int cnt = 0, off0 = 0, off4 = 0;
#pragma unroll
  for (int j = 0; j < 8; ++j) {
    if (j == w)     off0 = cnt;
    if (j == w + 4) off4 = cnt;
    cnt += cnt8[j];
  }
  if (mv0) idxs[off0 + __popcll(bal0 & ((1ull << lane) - 1ull))] = t;
  if (mv1) idxs[off4 + __popcll(bal1 & ((1ull << lane) - 1ull))] = t + 256;
  __syncthreads();

  const int c  = blockIdx.y;               // slot-chunk 0..3
  const int lo = (cnt * c) >> 2;
  const int hi = (cnt * (c + 1)) >> 2;
  const int NI = (hi - lo + 15) >> 4;      // 16-slot steps (<=8)
  const int g  = lane >> 4;
  const int c4 = (lane & 15) << 2;
  const int s00 = lo + (w << 2) + g;

  const float* vpb = vp + (size_t)b * 512 * 512;
  const float* qr0 = qp + (size_t)rowbase * 512;
  float* ow0 = out_w + (size_t)rowbase * 512;

  f32x2 Eq0a[8][2], Eq1a[8][2], wca[8][2];
#pragma unroll
  for (int j = 0; j < 8; ++j) {
    const int hoff = (j << 6) + c4;
    const float4 q0v = *(const float4*)(qr0 + hoff);
    const float4 q1v = *(const float4*)(qr0 + 512 + hoff);
    const float4 wcv = *(const float4*)(wc + hoff);
    Eq0a[j][0] = (f32x2){q0v.x, q0v.y}; Eq0a[j][1] = (f32x2){q0v.z, q0v.w};
    Eq1a[j][0] = (f32x2){q1v.x, q1v.y}; Eq1a[j][1] = (f32x2){q1v.z, q1v.w};
    wca[j][0]  = (f32x2){wcv.x, wcv.y}; wca[j][1]  = (f32x2){wcv.z, wcv.w};
  }

  int i0 = 0;
  for (; i0 + 4 <= NI; i0 += 4)
    score_chunkC<4>(vpb, Eq0a, Eq1a, wca, idxs, ow0, s00, i0, hi, c4, lane);
  for (; i0 < NI; ++i0)
    score_chunkC<1>(vpb, Eq0a, Eq1a, wca, idxs, ow0, s00, i0, hi, c4, lane);
}

// ---------------- attn kernel B: softmax + weights + context -----------------
__global__ __launch_bounds__(512) void attn_finish(
    const float* __restrict__ values, const int* __restrict__ mask,
    float* __restrict__ out_ctx, float* __restrict__ out_w)
{
  __shared__ int   idxs[512];
  __shared__ float wls2[512][2];    // final weights per slot, (q0,q1) pairs
  __shared__ int   cnt8[8];

  const int t    = threadIdx.x;
  const int lane = t & 63;
  const int w    = t >> 6;                 // 0..7
  const int b    = blockIdx.x & 7;
  const int qg   = blockIdx.x >> 3;
  const int rowbase = b * 128 + qg * 2;

  ((float*)wls2)[t]       = 0.f;
  ((float*)wls2)[t + 512] = 0.f;
  idxs[t] = 0;
  const int mv = mask[b * 512 + t];
  const unsigned long long bal = __ballot(mv != 0);
  if (lane == 0) cnt8[w] = __popcll(bal);
  __syncthreads();
  int cnt = 0, offw = 0;
#pragma unroll
  for (int j = 0; j < 8; ++j) { if (j == w) offw = cnt; cnt += cnt8[j]; }
  int iinv = -1;
  if (mv) {
    iinv = offw + __popcll(bal & ((1ull << lane) - 1ull));
    idxs[iinv] = t;
  }
  __syncthreads();

  // ---- softmax: waves 0-3 -> q0, 4-7 -> q1 (dup compute; waves 0/4 write)
  {
    const int mq = (w >= 4) ? 1 : 0;
    const float* srow = out_w + (size_t)(rowbase + mq) * 512;
    float4 u0 = ((const float4*)srow)[lane * 2];
    float4 u1 = ((const float4*)srow)[lane * 2 + 1];
    float s8[8] = {u0.x, u0.y, u0.z, u0.w, u1.x, u1.y, u1.z, u1.w};
#pragma unroll
    for (int k = 0; k < 8; ++k)
      if (lane * 8 + k >= cnt) s8[k] = 3.4e38f;           // mask garbage slots
    float m = s8[0];
#pragma unroll
    for (int k = 1; k < 8; ++k) m = fminf(m, s8[k]);      // min: weight=exp2(C*(m-s))
#pragma unroll
    for (int off = 1; off < 64; off <<= 1) m = fminf(m, __shfl_xor(m, off, 64));
    float e[8], S = 0.f;
#pragma unroll
    for (int k = 0; k < 8; ++k) { e[k] = fexp2(C_SCALE * (m - s8[k])); S += e[k]; }
#pragma unroll
    for (int off = 1; off < 64; off <<= 1) S += __shfl_xor(S, off, 64);
    const float rinv = frcp(S);
    if (w == 0 || w == 4) {
#pragma unroll
      for (int k = 0; k < 8; ++k) {
        const int s = lane * 8 + k;
        if (s < cnt) wls2[s][mq] = e[k] * rinv;
      }
    }
  }
  __syncthreads();

  // ---- final weight rows (coalesced; zeros where masked out)
  {
    float w0 = 0.f, w1 = 0.f;
    if (iinv >= 0) { w0 = wls2[iinv][0]; w1 = wls2[iinv][1]; }
    out_w[(size_t)rowbase * 512 + t]       = w0;
    out_w[(size_t)(rowbase + 1) * 512 + t] = w1;
  }

  // ---- context: wave w owns h-window [w*64, w*64+64)
  const int NC = (cnt + 3) >> 2;
  const int g  = lane >> 4;
  const int c4 = (lane & 15) << 2;
  const unsigned hbase = (unsigned)(w * 64 + c4);
  const float* vb = values + (size_t)b * 512 * 512;
  float c0[4] = {0.f, 0.f, 0.f, 0.f}, c1[4] = {0.f, 0.f, 0.f, 0.f};
#pragma unroll 4
  for (int i = 0; i < NC; ++i) {
    const int s = (i << 2) + g;
    const unsigned ro = ((unsigned)idxs[s] << 9) + hbase;
    const float2 wg = *(const float2*)&wls2[s][0];        // padded slots: 0
    const float4 v4 = *(const float4*)(vb + ro);
    float vv[4] = {v4.x, v4.y, v4.z, v4.w};
#pragma unroll
    for (int k = 0; k < 4; ++k) {
      c0[k] = __builtin_fmaf(wg.x, vv[k], c0[k]);
      c1[k] = __builtin_fmaf(wg.y, vv[k], c1[k]);
    }
  }
#pragma unroll
  for (int k = 0; k < 4; ++k) {                           // reduce over g
    c0[k] += __shfl_xor(c0[k], 16, 64); c0[k] += __shfl_xor(c0[k], 32, 64);
    c1[k] += __shfl_xor(c1[k], 16, 64); c1[k] += __shfl_xor(c1[k], 32, 64);
  }
  if (lane < 16) {
    float4 o0 = {c0[0], c0[1], c0[2], c0[3]};
    float4 o1 = {c1[0], c1[1], c1[2], c1[3]};
    *(float4*)(out_ctx + (size_t)rowbase * 512 + w * 64 + lane * 4)       = o0;
    *(float4*)(out_ctx + (size_t)(rowbase + 1) * 512 + w * 64 + lane * 4) = o1;
  }
}

extern "C" void kernel_launch(void* const* d_in, const int* in_sizes, int n_in,
                              void* d_out, int out_size, void* d_ws, size_t ws_size,
                              hipStream_t stream) {
  const float* query  = (const float*)d_in[0];
  const float* values = (const float*)d_in[1];
  const int*   mask   = (const int*)d_in[2];
  const float* Wq     = (const float*)d_in[3];
  const float* bq     = (const float*)d_in[4];
  const float* Wv     = (const float*)d_in[5];
  const float* bv     = (const float*)d_in[6];
  const float* wc     = (const float*)d_in[7];
  // d_in[8] = bc: no effect on outputs (softmax shift-invariance) -> dropped.

  float* out   = (float*)d_out;
  float* out_w = out + (size_t)8 * 128 * 512;
  float* qp    = (float*)d_ws;                 // Eq: 1024 x 512
  float* vp    = qp + (size_t)1024 * 512;      // Ev: 4096 x 512

  // presplit planes @10MB (R16): Ahi/Alo 5120x512, Whi/Wlo 1024x512 (bf16)
  const size_t base   = (size_t)(1024 + 4096) * 512;       // floats used
  const size_t needed = base * 4 /*Eq,Ev*/ +
                        ((size_t)5120 * 512 * 2 + (size_t)1024 * 512 * 2) * 2;
  if (ws_size >= needed) {
    short* Ahi = (short*)(vp + (size_t)4096 * 512);
    short* Alo = Ahi + (size_t)5120 * 512;
    short* Whi = Alo + (size_t)5120 * 512;
    short* Wlo = Whi + (size_t)1024 * 512;
    presplit<<<1536, 256, 0, stream>>>(query, values, Wq, Wv, Ahi, Alo, Whi, Wlo);
    proj_gemm_pre<<<dim3(8, 80), 256, 0, stream>>>(Ahi, Alo, Whi, Wlo,
                                                   bq, bv, qp, vp);
  } else {
    proj_gemm_mfma<<<dim3(8, 80), 256, 0, stream>>>(query, values, Wq, Wv,
                                                    bq, bv, qp, vp);
  }
  attn_score<<<dim3(512, 4), 256, 0, stream>>>(qp, vp, mask, wc, out_w);
  attn_finish<<<512, 512, 0, stream>>>(values, mask, out, out_w);
}

// Round 15
// 137.010 us; speedup vs baseline: 2.3598x; 1.0215x over previous
//
#include <hip/hip_runtime.h>
#include <hip/hip_bf16.h>

// AdditiveAttention: B=8, Q=128, V=512, H=512.
// out = [context (B*Q*H) | weights (B*Q*V)] fp32.
// ws: Eq [1024*512] f32 @0, Ev [4096*512] f32 @2MB (10MB total).
// bc dropped (softmax shift-invariant); sum_h wc[h] const also cancels.
// Score math: tanh(y)=1-2r, r=1/(2^(C*y)+1), C=2*log2(e);
//   softmax arg = -C * sum_h wc[h]*r  (consts dropped).
// HARD RULE (R0..R5): NO min-occupancy arg in launch_bounds, ever.
// HARD RULE (R12): NO hand-written VOP3P packed-f32 inline asm (silent
//   wrong results). Packed f32 only via <2 x float> source, backend-lowered.
// HARD RULE (R14): NO host memory APIs in kernel_launch (graph capture).
// HARD RULE (R15): NO per-block device-fence election (fused finish ran
//   242us vs 45us split -- __threadfence x2048 blocks serializes L2).
// R11: factorized exp (Ev=exp2(C*vp), Eq=exp2(C*qp) stored by proj) -- WIN.
// R13: f32x2 vector-source packed math -- WIN. Best measured: 137.1us.
// R16 (presplit): NEUTRAL (140.0) -- proj is latency-bound, not VALU-bound;
//   REVERTED. R17 = pure revert to the best-measured R13 configuration.
// Session verdict: proj/score/finish each latency-structure-bound; all
//   occupancy/schedule levers null; all math-removal levers exhausted.

#define C_SCALE 2.8853900817779268f

typedef __attribute__((ext_vector_type(8))) short short8;
typedef __attribute__((ext_vector_type(4))) float f32x4;
typedef __attribute__((ext_vector_type(2))) float f32x2;

__device__ __forceinline__ float fexp2(float x) { return __builtin_amdgcn_exp2f(x); }
__device__ __forceinline__ float frcp(float x)  { return __builtin_amdgcn_rcpf(x); }

// fp32->bf16 split: hi = RNE(x); lo = trunc_bf16(x - hi).
__device__ __forceinline__ void bf_split(float x, short& hi, short& lo) {
  unsigned u = __builtin_bit_cast(unsigned, x);
  unsigned r = u + 0x7fffu + ((u >> 16) & 1u);
  hi = (short)(r >> 16);
  float hf = __builtin_bit_cast(float, r & 0xffff0000u);
  lo = (short)(__builtin_bit_cast(unsigned, x - hf) >> 16);
}

// ---------------- split-bf16 MFMA GEMM ---------------------------------------
// acc[m][n] = sum_k A[m][k]*W[n][k] + bias[n]; OUTPUT = exp2(C*acc)  (R11).
// x = hi + lo (both bf16); D = Ahi*Whi + Ahi*Wlo + Alo*Whi (lo*lo dropped).
// 64x64 tile, KC=64. by<16 -> query rows (Eq), else values rows (Ev).
// LDS rows padded to 72 shorts (144B). Grid (8,80).
__global__ __launch_bounds__(256) void proj_gemm_mfma(
    const float* __restrict__ query, const float* __restrict__ values,
    const float* __restrict__ Wq, const float* __restrict__ Wv,
    const float* __restrict__ bq, const float* __restrict__ bv,
    float* __restrict__ qp, float* __restrict__ vp)
{
  __shared__ short sAhi[64 * 72];
  __shared__ short sAlo[64 * 72];
  __shared__ short sWhi[64 * 72];
  __shared__ short sWlo[64 * 72];

  const int t    = threadIdx.x;
  const int lane = t & 63;
  const int w    = t >> 6;                  // wave 0..3
  const int by   = blockIdx.y;
  const bool isQ = (by < 16);
  const float* A    = isQ ? query : values;
  const float* W    = isQ ? Wq : Wv;
  const float* bias = isQ ? bq : bv;
  float*       out  = isQ ? qp : vp;
  const int m0 = (isQ ? by : (by - 16)) << 6;
  const int n0 = blockIdx.x << 6;

  const int srow = t >> 2, scol = t & 3;
  const float* Ap = A + (size_t)(m0 + srow) * 512 + (scol << 2);
  const float* Wp = W + (size_t)(n0 + srow) * 512 + (scol << 2);

  const int mw = (w & 1) << 5, nw = (w >> 1) << 5;   // wave's 32x32 quadrant
  const int frow = lane & 15, fquad = lane >> 4;

  f32x4 acc[2][2] = {};
  float4 pfA[4], pfW[4];
#pragma unroll
  for (int p = 0; p < 4; ++p) {
    pfA[p] = *(const float4*)(Ap + (p << 4));
    pfW[p] = *(const float4*)(Wp + (p << 4));
  }

  for (int kc = 0; kc < 512; kc += 64) {
    __syncthreads();
#pragma unroll
    for (int p = 0; p < 4; ++p) {
      float av[4] = {pfA[p].x, pfA[p].y, pfA[p].z, pfA[p].w};
      float wv[4] = {pfW[p].x, pfW[p].y, pfW[p].z, pfW[p].w};
      short4 ah, al, wh, wl;
      short* ahp = (short*)&ah; short* alp = (short*)&al;
      short* whp = (short*)&wh; short* wlp = (short*)&wl;
#pragma unroll
      for (int k = 0; k < 4; ++k) {
        bf_split(av[k], ahp[k], alp[k]);
        bf_split(wv[k], whp[k], wlp[k]);
      }
      const int ofs = srow * 72 + ((p << 2) + scol) * 4;
      *(short4*)&sAhi[ofs] = ah; *(short4*)&sAlo[ofs] = al;
      *(short4*)&sWhi[ofs] = wh; *(short4*)&sWlo[ofs] = wl;
    }
    __syncthreads();
    if (kc + 64 < 512) {
#pragma unroll
      for (int p = 0; p < 4; ++p) {
        pfA[p] = *(const float4*)(Ap + kc + 64 + (p << 4));
        pfW[p] = *(const float4*)(Wp + kc + 64 + (p << 4));
      }
    }
#pragma unroll
    for (int kb = 0; kb < 2; ++kb) {
      const int ko = kb * 32 + fquad * 8;
      short8 ahi[2], alo[2], whi[2], wlo[2];
#pragma unroll
      for (int mt = 0; mt < 2; ++mt) {
        const int r = (mw + mt * 16 + frow) * 72 + ko;
        ahi[mt] = *(const short8*)&sAhi[r];
        alo[mt] = *(const short8*)&sAlo[r];
      }
#pragma unroll
      for (int nt = 0; nt < 2; ++nt) {
        const int r = (nw + nt * 16 + frow) * 72 + ko;
        whi[nt] = *(const short8*)&sWhi[r];
        wlo[nt] = *(const short8*)&sWlo[r];
      }
#pragma unroll
      for (int mt = 0; mt < 2; ++mt)
#pragma unroll
        for (int nt = 0; nt < 2; ++nt) {
          acc[mt][nt] = __builtin_amdgcn_mfma_f32_16x16x32_bf16(
              alo[mt], whi[nt], acc[mt][nt], 0, 0, 0);
          acc[mt][nt] = __builtin_amdgcn_mfma_f32_16x16x32_bf16(
              ahi[mt], wlo[nt], acc[mt][nt], 0, 0, 0);
          acc[mt][nt] = __builtin_amdgcn_mfma_f32_16x16x32_bf16(
              ahi[mt], whi[nt], acc[mt][nt], 0, 0, 0);
        }
    }
  }

  // epilogue: C/D layout col = lane&15, row = (lane>>4)*4 + reg.
  // R11: store exp2(C*(acc+bias)) -- Eq/Ev consumed multiplicatively by score.
#pragma unroll
  for (int nt = 0; nt < 2; ++nt) {
    const int n = n0 + nw + nt * 16 + frow;
    const float bn = bias[n];
#pragma unroll
    for (int mt = 0; mt < 2; ++mt) {
      float vreg[4] = {acc[mt][nt].x, acc[mt][nt].y, acc[mt][nt].z, acc[mt][nt].w};
#pragma unroll
      for (int r = 0; r < 4; ++r) {
        const int m = m0 + mw + mt * 16 + fquad * 4 + r;
        out[(size_t)m * 512 + n] = fexp2(C_SCALE * (vreg[r] + bn));
      }
    }
  }
}

// ---------------- score chunk (NU slot-steps, 16 slots apart) ----------------
// f32x2 vector arithmetic (backend lowers to v_pk_*; NO inline asm).
template<int NU>
__device__ __forceinline__ void score_chunkC(
    const float* __restrict__ vpb,
    const f32x2 (&Eq0a)[8][2], const f32x2 (&Eq1a)[8][2], const f32x2 (&wca)[8][2],
    const int* idxs, float* __restrict__ ow0,
    int s00, int i0, int hi, int c4, int lane)
{
  int su[NU];
  unsigned voff[NU];
  f32x2 a0[NU], a1[NU];
#pragma unroll
  for (int u = 0; u < NU; ++u) {
    su[u] = s00 + ((i0 + u) << 4);
    voff[u] = ((unsigned)idxs[su[u] & 511] << 9) + (unsigned)c4;
    a0[u] = (f32x2){0.f, 0.f}; a1[u] = (f32x2){0.f, 0.f};
  }
  const f32x2 one2 = {1.f, 1.f};
#pragma unroll
  for (int j = 0; j < 8; ++j) {
    float4 vv[NU];
#pragma unroll
    for (int u = 0; u < NU; ++u)
      vv[u] = *(const float4*)(vpb + voff[u] + (unsigned)(j << 6));
#pragma unroll
    for (int u = 0; u < NU; ++u) {
      const f32x2 Ev[2] = {{vv[u].x, vv[u].y}, {vv[u].z, vv[u].w}};
#pragma unroll
      for (int kp = 0; kp < 2; ++kp) {
        f32x2 e0 = Ev[kp] * Eq0a[j][kp];
        f32x2 e1 = Ev[kp] * Eq1a[j][kp];
        f32x2 d0 = e0 + one2;
        f32x2 d1 = e1 + one2;
        f32x2 pr = d0 * d1;
        f32x2 P  = {frcp(pr.x), frcp(pr.y)};       // pair-rcp per q-pair
        a0[u] = __builtin_elementwise_fma(wca[j][kp] * d1, P, a0[u]);
        a1[u] = __builtin_elementwise_fma(wca[j][kp] * d0, P, a1[u]);
      }
    }
  }
#pragma unroll
  for (int u = 0; u < NU; ++u) {
    float s0 = a0[u].x + a0[u].y;
    float s1 = a1[u].x + a1[u].y;
#pragma unroll
    for (int off = 1; off < 16; off <<= 1) {
      s0 += __shfl_xor(s0, off, 64);
      s1 += __shfl_xor(s1, off, 64);
    }
    if (su[u] < hi && (lane & 15) == (i0 + u)) {   // i0+u <= 7 < 16
      ow0[su[u]]       = s0;
      ow0[512 + su[u]] = s1;
    }
  }
}

// ---------------- attn kernel A: raw scores ----------------------------------
// Grid (512 qpairs, 4 slot-chunks) x 256 thr (4 waves). PLAIN launch_bounds.
// Block covers slots [cnt*c/4, cnt*(c+1)/4); wave w, iter i owns slots
// lo + i*16 + w*4 + g (g = lane>>4); 16 h-lanes per slot (c4 = (lane&15)*4).
// Raw scores written slot-ordered into out_w rows (staging; finish rewrites).
__global__ __launch_bounds__(256) void attn_score(
    const float* __restrict__ qp, const float* __restrict__ vp,
    const int* __restrict__ mask, const float* __restrict__ wc,
    float* __restrict__ out_w)
{
  __shared__ int idxs[512];
  __shared__ int cnt8[8];

  const int t    = threadIdx.x;
  const int lane = t & 63;
  const int w    = t >> 6;                 // 0..3
  const int b    = blockIdx.x & 7;
  const int qg   = blockIdx.x >> 3;
  const int rowbase = b * 128 + qg * 2;

  idxs[t] = 0; idxs[t + 256] = 0;
  const int mv0 = mask[b * 512 + t];
  const int mv1 = mask[b * 512 + 256 + t];
  const unsigned long long bal0 = __ballot(mv0 != 0);
  const unsigned long long bal1 = __ballot(mv1 != 0);
  if (lane == 0) { cnt8[w] = __popcll(bal0); cnt8[w + 4] = __popcll(bal1); }
  __syncthreads();
  int cnt = 0, off0 = 0, off4 = 0;
#pragma unroll
  for (int j = 0; j < 8; ++j) {
    if (j == w)     off0 = cnt;
    if (j == w + 4) off4 = cnt;
    cnt += cnt8[j];
  }
  if (mv0) idxs[off0 + __popcll(bal0 & ((1ull << lane) - 1ull))] = t;
  if (mv1) idxs[off4 + __popcll(bal1 & ((1ull << lane) - 1ull))] = t + 256;
  __syncthreads();

  const int c  = blockIdx.y;               // slot-chunk 0..3
  const int lo = (cnt * c) >> 2;
  const int hi = (cnt * (c + 1)) >> 2;
  const int NI = (hi - lo + 15) >> 4;      // 16-slot steps (<=8)
  const int g  = lane >> 4;
  const int c4 = (lane & 15) << 2;
  const int s00 = lo + (w << 2) + g;

  const float* vpb = vp + (size_t)b * 512 * 512;
  const float* qr0 = qp + (size_t)rowbase * 512;
  float* ow0 = out_w + (size_t)rowbase * 512;

  // ---- hoist per-block Eq-state for all 8 j's (96 regs, static indices)
  f32x2 Eq0a[8][2], Eq1a[8][2], wca[8][2];
#pragma unroll
  for (int j = 0; j < 8; ++j) {
    const int hoff = (j << 6) + c4;
    const float4 q0v = *(const float4*)(qr0 + hoff);
    const float4 q1v = *(const float4*)(qr0 + 512 + hoff);
    const float4 wcv = *(const float4*)(wc + hoff);
    Eq0a[j][0] = (f32x2){q0v.x, q0v.y}; Eq0a[j][1] = (f32x2){q0v.z, q0v.w};
    Eq1a[j][0] = (f32x2){q1v.x, q1v.y}; Eq1a[j][1] = (f32x2){q1v.z, q1v.w};
    wca[j][0]  = (f32x2){wcv.x, wcv.y}; wca[j][1]  = (f32x2){wcv.z, wcv.w};
  }

  int i0 = 0;
  for (; i0 + 4 <= NI; i0 += 4)
    score_chunkC<4>(vpb, Eq0a, Eq1a, wca, idxs, ow0, s00, i0, hi, c4, lane);
  for (; i0 < NI; ++i0)
    score_chunkC<1>(vpb, Eq0a, Eq1a, wca, idxs, ow0, s00, i0, hi, c4, lane);
}

// ---------------- attn kernel B: softmax + weights + context -----------------
// 512 blocks x 512 thr (8 waves). Reads slot-ordered raw scores from out_w,
// softmax (min-shift, invalid slots masked to +BIG), rewrites out_w rows
// coalesced via inverse map, context with wave-per-h-window.
__global__ __launch_bounds__(512) void attn_finish(
    const float* __restrict__ values, const int* __restrict__ mask,
    float* __restrict__ out_ctx, float* __restrict__ out_w)
{
  __shared__ int   idxs[512];
  __shared__ float wls2[512][2];    // final weights per slot, (q0,q1) pairs
  __shared__ int   cnt8[8];

  const int t    = threadIdx.x;
  const int lane = t & 63;
  const int w    = t >> 6;                 // 0..7
  const int b    = blockIdx.x & 7;
  const int qg   = blockIdx.x >> 3;
  const int rowbase = b * 128 + qg * 2;

  ((float*)wls2)[t]       = 0.f;
  ((float*)wls2)[t + 512] = 0.f;
  idxs[t] = 0;
  const int mv = mask[b * 512 + t];
  const unsigned long long bal = __ballot(mv != 0);
  if (lane == 0) cnt8[w] = __popcll(bal);
  __syncthreads();
  int cnt = 0, offw = 0;
#pragma unroll
  for (int j = 0; j < 8; ++j) { if (j == w) offw = cnt; cnt += cnt8[j]; }
  int iinv = -1;
  if (mv) {
    iinv = offw + __popcll(bal & ((1ull << lane) - 1ull));
    idxs[iinv] = t;
  }
  __syncthreads();

  // ---- softmax: waves 0-3 -> q0, 4-7 -> q1 (dup compute; waves 0/4 write)
  {
    const int mq = (w >= 4) ? 1 : 0;
    const float* srow = out_w + (size_t)(rowbase + mq) * 512;
    float4 u0 = ((const float4*)srow)[lane * 2];
    float4 u1 = ((const float4*)srow)[lane * 2 + 1];
    float s8[8] = {u0.x, u0.y, u0.z, u0.w, u1.x, u1.y, u1.z, u1.w};
#pragma unroll
    for (int k = 0; k < 8; ++k)
      if (lane * 8 + k >= cnt) s8[k] = 3.4e38f;           // mask garbage slots
    float m = s8[0];
#pragma unroll
    for (int k = 1; k < 8; ++k) m = fminf(m, s8[k]);      // min: weight=exp2(C*(m-s))
#pragma unroll
    for (int off = 1; off < 64; off <<= 1) m = fminf(m, __shfl_xor(m, off, 64));
    float e[8], S = 0.f;
#pragma unroll
    for (int k = 0; k < 8; ++k) { e[k] = fexp2(C_SCALE * (m - s8[k])); S += e[k]; }
#pragma unroll
    for (int off = 1; off < 64; off <<= 1) S += __shfl_xor(S, off, 64);
    const float rinv = frcp(S);
    if (w == 0 || w == 4) {
#pragma unroll
      for (int k = 0; k < 8; ++k) {
        const int s = lane * 8 + k;
        if (s < cnt) wls2[s][mq] = e[k] * rinv;
      }
    }
  }
  __syncthreads();

  // ---- final weight rows (coalesced; zeros where masked out)
  {
    float w0 = 0.f, w1 = 0.f;
    if (iinv >= 0) { w0 = wls2[iinv][0]; w1 = wls2[iinv][1]; }
    out_w[(size_t)rowbase * 512 + t]       = w0;
    out_w[(size_t)(rowbase + 1) * 512 + t] = w1;
  }

  // ---- context: wave w owns h-window [w*64, w*64+64)
  const int NC = (cnt + 3) >> 2;
  const int g  = lane >> 4;
  const int c4 = (lane & 15) << 2;
  const unsigned hbase = (unsigned)(w * 64 + c4);
  const float* vb = values + (size_t)b * 512 * 512;
  float c0[4] = {0.f, 0.f, 0.f, 0.f}, c1[4] = {0.f, 0.f, 0.f, 0.f};
#pragma unroll 4
  for (int i = 0; i < NC; ++i) {
    const int s = (i << 2) + g;
    const unsigned ro = ((unsigned)idxs[s] << 9) + hbase;
    const float2 wg = *(const float2*)&wls2[s][0];        // padded slots: 0
    const float4 v4 = *(const float4*)(vb + ro);
    float vv[4] = {v4.x, v4.y, v4.z, v4.w};
#pragma unroll
    for (int k = 0; k < 4; ++k) {
      c0[k] = __builtin_fmaf(wg.x, vv[k], c0[k]);
      c1[k] = __builtin_fmaf(wg.y, vv[k], c1[k]);
    }
  }
#pragma unroll
  for (int k = 0; k < 4; ++k) {                           // reduce over g
    c0[k] += __shfl_xor(c0[k], 16, 64); c0[k] += __shfl_xor(c0[k], 32, 64);
    c1[k] += __shfl_xor(c1[k], 16, 64); c1[k] += __shfl_xor(c1[k], 32, 64);
  }
  if (lane < 16) {
    float4 o0 = {c0[0], c0[1], c0[2], c0[3]};
    float4 o1 = {c1[0], c1[1], c1[2], c1[3]};
    *(float4*)(out_ctx + (size_t)rowbase * 512 + w * 64 + lane * 4)       = o0;
    *(float4*)(out_ctx + (size_t)(rowbase + 1) * 512 + w * 64 + lane * 4) = o1;
  }
}

extern "C" void kernel_launch(void* const* d_in, const int* in_sizes, int n_in,
                              void* d_out, int out_size, void* d_ws, size_t ws_size,
                              hipStream_t stream) {
  const float* query  = (const float*)d_in[0];
  const float* values = (const float*)d_in[1];
  const int*   mask   = (const int*)d_in[2];
  const float* Wq     = (const float*)d_in[3];
  const float* bq     = (const float*)d_in[4];
  const float* Wv     = (const float*)d_in[5];
  const float* bv     = (const float*)d_in[6];
  const float* wc     = (const float*)d_in[7];
  // d_in[8] = bc: no effect on outputs (softmax shift-invariance) -> dropped.

  float* out   = (float*)d_out;
  float* out_w = out + (size_t)8 * 128 * 512;
  float* qp    = (float*)d_ws;                 // Eq: 1024 x 512
  float* vp    = qp + (size_t)1024 * 512;      // Ev: 4096 x 512

  proj_gemm_mfma<<<dim3(8, 80), 256, 0, stream>>>(query, values, Wq, Wv, bq, bv, qp, vp);
  attn_score<<<dim3(512, 4), 256, 0, stream>>>(qp, vp, mask, wc, out_w);
  attn_finish<<<512, 512, 0, stream>>>(values, mask, out, out_w);
}